// Round 9
// baseline (66.419 us; speedup 1.0000x reference)
//
#include <hip/hip_runtime.h>

// MultiHeadDense: out[b] = x[b] @ W[idx[b]] + bias[idx[b]]
// B=4096, D=1024, F=1024, H=8. fp32 in/out; bf16 MFMA internally.
// Round 9: m97-clone GEMM. BK=32, linear LDS (no swizzle, m97 tolerates the
// conflicts), 32KB dbuf -> 3 resident blocks/CU (12 waves), split-K-2 ->
// ~1024 working blocks, 134 MB staged (BN=128). Counted vmcnt(4). Atomic
// epilogue onto bias-pre-initialized out (r8-proven). Plain Wt/Ap layouts.

typedef __attribute__((ext_vector_type(8))) short bf16x8;
typedef __attribute__((ext_vector_type(4))) float f32x4;

#define WAITV(N) asm volatile("s_waitcnt vmcnt(" #N ")" ::: "memory")

static __device__ __forceinline__ unsigned short f2bf(float f) {
  union { float f; unsigned int u; } c; c.f = f;
  unsigned int u = c.u;
  return (unsigned short)((u + 0x7fffu + ((u >> 16) & 1u)) >> 16);
}

static __device__ __forceinline__ void gload16(const void* g, void* s) {
  __builtin_amdgcn_global_load_lds(
      (const __attribute__((address_space(1))) void*)g,
      (__attribute__((address_space(3))) void*)s, 16, 0, 0);
}

// Kernel 1 (fused): blocks 0..2047 transpose+convert W [H][D][F] fp32 ->
// Wt [H][F][D] bf16 (plain row-major). Block 2048: counting-sort scan of
// idx -> rows[] + cnt[] + base8[] (8-aligned head bases; gaps zero-filled).
__global__ __launch_bounds__(256) void k_prep(
    const float* __restrict__ W, const int* __restrict__ idx,
    unsigned short* __restrict__ Wt, int* __restrict__ cnt,
    int* __restrict__ base8, int* __restrict__ rows) {
  const int bid = blockIdx.x;
  const int t = threadIdx.x;

  if (bid >= 2048) {
    __shared__ int sc[256][8];
    int myi[16];
#pragma unroll
    for (int i = 0; i < 4; ++i) {
      const int4 v = *(const int4*)(idx + t * 16 + i * 4);
      myi[i * 4 + 0] = v.x; myi[i * 4 + 1] = v.y;
      myi[i * 4 + 2] = v.z; myi[i * 4 + 3] = v.w;
    }
    int c[8];
#pragma unroll
    for (int h = 0; h < 8; ++h) c[h] = 0;
#pragma unroll
    for (int e = 0; e < 16; ++e)
#pragma unroll
      for (int h = 0; h < 8; ++h) c[h] += (myi[e] == h) ? 1 : 0;

    int val[8];
#pragma unroll
    for (int h = 0; h < 8; ++h) { val[h] = c[h]; sc[t][h] = c[h]; }
    __syncthreads();
    for (int off = 1; off < 256; off <<= 1) {
      int nb[8];
#pragma unroll
      for (int h = 0; h < 8; ++h) nb[h] = (t >= off) ? sc[t - off][h] : 0;
      __syncthreads();
#pragma unroll
      for (int h = 0; h < 8; ++h) { val[h] += nb[h]; sc[t][h] = val[h]; }
      __syncthreads();
    }
    int tot[8], excl[8];
#pragma unroll
    for (int h = 0; h < 8; ++h) tot[h] = sc[255][h];
#pragma unroll
    for (int h = 0; h < 8; ++h) excl[h] = val[h] - c[h];
    int bases[9];
    bases[0] = 0;
#pragma unroll
    for (int h = 0; h < 7; ++h) bases[h + 1] = (bases[h] + tot[h] + 7) & ~7;
    bases[8] = bases[7] + tot[7];
#pragma unroll
    for (int h = 0; h < 8; ++h) {
      int pos = bases[h] + excl[h];
#pragma unroll
      for (int e = 0; e < 16; ++e) {
        if (myi[e] == h) { rows[pos] = t * 16 + e; ++pos; }
      }
    }
    if (t < 56) {
      const int hh = t >> 3, j = t & 7;
      const int pos = bases[hh] + tot[hh] + j;
      if (pos < bases[hh + 1]) rows[pos] = 0;
    }
    if (t < 128) {
      const int pos = bases[8] + t;
      if (pos < 4160) rows[pos] = 0;
    }
    if (t < 8) cnt[t] = tot[t];
    if (t == 0) {
#pragma unroll
      for (int h = 0; h < 9; ++h) base8[h] = bases[h];
    }
    return;
  }

  // ---- transpose block: 64x64 tile of head h ----
  __shared__ unsigned short tile[64][68];
  const int h = bid >> 8;
  const int rem = bid & 255;
  const int d0 = (rem >> 4) << 6;
  const int f0 = (rem & 15) << 6;
  const int c4 = (t & 15) * 4;
  const int r0 = t >> 4;
#pragma unroll
  for (int i = 0; i < 4; ++i) {
    const int r = r0 + i * 16;
    const float4 v = *(const float4*)(W + (size_t)(h * 1024 + d0 + r) * 1024 + f0 + c4);
    tile[r][c4 + 0] = f2bf(v.x);
    tile[r][c4 + 1] = f2bf(v.y);
    tile[r][c4 + 2] = f2bf(v.z);
    tile[r][c4 + 3] = f2bf(v.w);
  }
  __syncthreads();
#pragma unroll
  for (int i = 0; i < 4; ++i) {
    const int fr = r0 + i * 16;
    ushort4 o;
    o.x = tile[c4 + 0][fr];
    o.y = tile[c4 + 1][fr];
    o.z = tile[c4 + 2][fr];
    o.w = tile[c4 + 3][fr];
    *(ushort4*)(Wt + (size_t)(h * 1024 + f0 + fr) * 1024 + d0 + c4) = o;
  }
}

// Kernel 2: plain gather-copy X row rows[slot] -> Ap[slot] bf16, AND
// pre-init out[b] = bias[idx[b]] (GEMM epilogue accumulates onto this).
// Pad slots re-init row 0 idempotently - harmless.
__global__ __launch_bounds__(256) void k_gather(
    const float* __restrict__ X, const int* __restrict__ idx,
    const int* __restrict__ rows, unsigned short* __restrict__ Ap,
    const float* __restrict__ bias, float* __restrict__ out) {
  const int slot = blockIdx.x;
  const int b = rows[slot];
  const int t = threadIdx.x;
  const float4 v = *(const float4*)(X + (size_t)b * 1024 + t * 4);
  ushort4 o;
  o.x = f2bf(v.x); o.y = f2bf(v.y); o.z = f2bf(v.z); o.w = f2bf(v.w);
  *(ushort4*)(Ap + (size_t)slot * 1024 + t * 4) = o;
  const int h = idx[b];
  const float4 bv = *(const float4*)(bias + h * 1024 + t * 4);
  *(float4*)(out + (size_t)b * 1024 + t * 4) = bv;
}

// Kernel 3: grouped GEMM, m97-structure. 128x128 tile, BK=32, split-K-2
// (K=512/block, 16 steps). 4 waves (2x2, each 64x64, 4x4 frag accs).
// LDS 32KB dbuf (linear, unswizzled - m97 parity), counted vmcnt(4).
// 3 resident blocks/CU. h=blk&7 -> XCD affinity; within (h,mt,ks) the 8
// nt-blocks are dispatch-adjacent so the A panel stays hot in L2.
// Epilogue: unsafeAtomicAdd onto bias-pre-initialized out.
__global__ __launch_bounds__(256) void k_gemm(
    const unsigned short* __restrict__ Ap, const unsigned short* __restrict__ Wt,
    const int* __restrict__ rows, const int* __restrict__ cnt,
    const int* __restrict__ base8,
    float* __restrict__ out) {
  __shared__ __align__(16) unsigned short As[2][128 * 32];  // 8KB per buf
  __shared__ __align__(16) unsigned short Bs[2][128 * 32];

  const int blk = blockIdx.x;
  const int h = blk & 7;           // head -> XCD affinity
  const int nt = (blk >> 3) & 7;   // 8 n-tiles of 128
  const int ks = (blk >> 6) & 1;   // K-split half
  const int mt = blk >> 7;         // up to 16 m-tiles of 128

  const int cnt_h = cnt[h];
  const int basep = base8[h];
  const int m0 = mt * 128;
  if (m0 >= cnt_h) return;
  const int n0 = nt * 128;
  const int kb = ks * 512;         // this block's K base (elements)

  const int t = threadIdx.x;
  const int lane = t & 63;
  const int wave = t >> 6;
  const int wr = wave >> 1, wc = wave & 1;  // wave tile: 64x64

  // Staging sources: instr covers 64 rows; thread t -> row t>>2, chunk t&3.
  // dest byte = t*16 (linear LDS, 64B rows).
  const int srow = t >> 2;
  const int schunk = (t & 3) << 4;  // byte offset within 64B k-slice
  const char* aSrc0 = (const char*)Ap + (size_t)(basep + m0 + srow) * 2048 + schunk;
  const char* aSrc1 = aSrc0 + (size_t)64 * 2048;
  const char* bSrc0 = (const char*)Wt + (size_t)(h * 1024 + n0 + srow) * 2048 + schunk;
  const char* bSrc1 = bSrc0 + (size_t)64 * 2048;

  f32x4 acc[4][4];
#pragma unroll
  for (int m = 0; m < 4; ++m)
#pragma unroll
    for (int n = 0; n < 4; ++n)
      acc[m][n] = (f32x4){0.f, 0.f, 0.f, 0.f};

  auto stage = [&](int s, int k0) {  // 4 gload16 per thread
    const int kby = k0 * 2;
    gload16(aSrc0 + kby, (char*)(&As[s][0]) + t * 16);
    gload16(aSrc1 + kby, (char*)(&As[s][0]) + 4096 + t * 16);
    gload16(bSrc0 + kby, (char*)(&Bs[s][0]) + t * 16);
    gload16(bSrc1 + kby, (char*)(&Bs[s][0]) + 4096 + t * 16);
  };

  // frag read bases: row*64B + kgroup*16B (linear; 8-way conflicts accepted)
  const int ra = (wr * 64 + (lane & 15)) * 64 + (lane >> 4) * 16;
  const int rb = (wc * 64 + (lane & 15)) * 64 + (lane >> 4) * 16;

  auto compute = [&](int s) {
    const char* ab = (const char*)(&As[s][0]);
    const char* bb = (const char*)(&Bs[s][0]);
    bf16x8 af[4], bfr[4];
#pragma unroll
    for (int m = 0; m < 4; ++m)
      af[m] = *(const bf16x8*)(ab + ra + m * 1024);
#pragma unroll
    for (int n = 0; n < 4; ++n)
      bfr[n] = *(const bf16x8*)(bb + rb + n * 1024);
#pragma unroll
    for (int m = 0; m < 4; ++m)
#pragma unroll
      for (int n = 0; n < 4; ++n)
        acc[m][n] = __builtin_amdgcn_mfma_f32_16x16x32_bf16(af[m], bfr[n], acc[m][n], 0, 0, 0);
  };

  stage(0, kb);
  stage(1, kb + 32);

  for (int ts = 0; ts < 14; ++ts) {
    WAITV(4);                         // stage ts landed; ts+1 stays in flight
    __builtin_amdgcn_s_barrier();
    __builtin_amdgcn_sched_barrier(0);
    compute(ts & 1);
    __builtin_amdgcn_s_barrier();     // all waves done reading buf ts&1
    __builtin_amdgcn_sched_barrier(0);
    stage(ts & 1, kb + (ts + 2) * 32);
    __builtin_amdgcn_sched_barrier(0);
  }
  WAITV(4);
  __builtin_amdgcn_s_barrier();
  __builtin_amdgcn_sched_barrier(0);
  compute(0);
  WAITV(0);
  __builtin_amdgcn_s_barrier();
  __builtin_amdgcn_sched_barrier(0);
  compute(1);

  // Epilogue: atomic-accumulate partials onto bias-pre-initialized out.
  int rmap[4][4];
  bool vld[4][4];
#pragma unroll
  for (int m = 0; m < 4; ++m) {
#pragma unroll
    for (int j = 0; j < 4; ++j) {
      const int lr = wr * 64 + m * 16 + (lane >> 4) * 4 + j;
      const bool v = (m0 + lr) < cnt_h;
      vld[m][j] = v;
      rmap[m][j] = v ? rows[basep + m0 + lr] : 0;
    }
  }
#pragma unroll
  for (int n = 0; n < 4; ++n) {
    const int c = n0 + wc * 64 + n * 16 + (lane & 15);
#pragma unroll
    for (int m = 0; m < 4; ++m) {
#pragma unroll
      for (int j = 0; j < 4; ++j) {
        if (vld[m][j])
          unsafeAtomicAdd(&out[(size_t)rmap[m][j] * 1024 + c], acc[m][n][j]);
      }
    }
  }
}

extern "C" void kernel_launch(void* const* d_in, const int* in_sizes, int n_in,
                              void* d_out, int out_size, void* d_ws, size_t ws_size,
                              hipStream_t stream) {
  const float* X = (const float*)d_in[0];
  const int* idx = (const int*)d_in[1];
  const float* W = (const float*)d_in[2];
  const float* bias = (const float*)d_in[3];
  float* out = (float*)d_out;

  char* ws = (char*)d_ws;
  int* cnt = (int*)ws;                                   // 8 ints @ 0
  int* base8 = (int*)(ws + 64);                          // 9 ints @ 64
  int* rows = (int*)(ws + 256);                          // 4160 ints
  unsigned short* Wt = (unsigned short*)(ws + 32768);    // 8M bf16 = 16 MB
  unsigned short* Ap = (unsigned short*)(ws + 32768 + 16777216);  // 4352 rows * 2KB

  k_prep<<<dim3(2049), 256, 0, stream>>>(W, idx, Wt, cnt, base8, rows);
  k_gather<<<dim3(4160), 256, 0, stream>>>(X, idx, rows, Ap, bias, out);
  // 8 heads (xcd-affine) x 8 nt x 2 k-halves x 16 mt (early-return past cnt_h)
  k_gemm<<<dim3(8 * 8 * 2 * 16), 256, 0, stream>>>(Ap, Wt, rows, cnt, base8, out);
}